// Round 1
// 190.121 us; speedup vs baseline: 1.0041x; 1.0041x over previous
//
#include <hip/hip_runtime.h>

// ValueDVHLoss via the Wasserstein/CDF identity:
//   sum_i |a_(i) - b_(i)| = integral |#{a<=t} - #{b<=t}| dt
// R13: break the per-tile full-drain convoy in hist. R9 structure did
// issue-28-DMA / __syncthreads (vmcnt(0) drain!) / compute / __syncthreads
// per tile -- no load survives a barrier, so all 512 blocks run 4 serialized
// chip-wide burst+drain rounds => 50us at 18% HBM, "all pipes <20%".
// Fix (T3/T4): depth-2 pipeline, triple-buffered 14KB tiles (TILE=1024,
// NTILE=8), raw s_barrier + counted inline-asm s_waitcnt vmcnt(2/1) (never 0
// except last tile). Prefetch issued AFTER the barrier (can't overwrite the
// buffer the previous compute read); vmcnt(0)+lgkmcnt(0) drained once before
// the prologue (ws-zero STORES count against vmcnt; hist-zero LDS writes need
// publishing). LDS 66KB/block -> still 2 blocks/CU. seg_scan unchanged.

#define NBINS 1024
#define NB1   (NBINS - 1)
#define RROI  6
#define BPAT  4
#define NSEG  24                 // seg = r*BPAT + b
#define VVOX  1048576            // voxels per patient (C=1)
#define BLKP  128                // hist blocks per patient
#define GRID1 (BPAT * BLKP)      // 512 blocks = 2/CU
#define CHUNK (VVOX / BLKP)      // 8192 voxels per block
#define TILE  1024               // voxels per DMA tile
#define NTILE (CHUNK / TILE)     // 8
#define NBUF  3                  // triple buffer, depth-2 prefetch
#define NSLOT 14                 // 4 pred + 4 tgt + 6 mask, 1KB each
#define HW    (NBINS / 2)        // 512 packed words per (block,roi)

// LDS layout (int indices): hist 6x1024 @ 0 (24KB);
// 3 tile buffers @ 6144, each 3584 ints (14KB):
//   pred 1024 @ +0, tgt 1024 @ +1024, mask 6x256 @ +2048
#define BUF0_I 6144
#define BUFSZ  3584
#define LDS_INTS (BUF0_I + NBUF * BUFSZ)   // 16896 ints = 66 KB
#define BUF_I  6144              // merge scratch (buffer 0, free after loop)

// ws layout (int indices)
#define PART_I 0
#define PART_N (GRID1 * RROI * HW)        // 1,572,864 ints (6.3 MB)
#define CNT6_I (PART_I + PART_N)
#define CNT6_N (GRID1 * RROI)             // 3072
#define FH_I   (CNT6_I + CNT6_N)
#define FH_N   (NSEG * NBINS)             // 24576
#define DONE_I (FH_I + FH_N)              // 24
#define SEGD_I (DONE_I + NSEG)            // 1
#define ZERO_I FH_I
#define ZERO_N (FH_N + NSEG + 1)          // 24601 (zeroed by hist blocks)
#define S_I    (SEGD_I + 1)               // 24 floats
#define DEN_I  (S_I + NSEG)               // 24

typedef __attribute__((address_space(1))) const void glb_t;
typedef __attribute__((address_space(3))) void lds_t;

#define VWAIT(S) asm volatile("s_waitcnt " S ::: "memory")
#define CFENCE() asm volatile("" ::: "memory")

// ---- phase 1: per-chunk histogram over all 6 ROIs, pipelined DMA ---------
__global__ __launch_bounds__(512, 4) void hist_kernel(
    const float* __restrict__ pred, const float* __restrict__ tgt,
    const void* __restrict__ mask, int* __restrict__ ws) {
  __shared__ __align__(16) int lds[LDS_INTS];   // 66 KB
  const int tid  = threadIdx.x;
  const int lane = tid & 63;
  const int wid  = tid >> 6;            // 8 waves
  const int flat = blockIdx.x;          // 0..511
  const int b    = flat >> 7;           // patient
  const int nb   = flat & (BLKP - 1);
  const int v0   = nb * CHUNK;

  const unsigned int* mwp = (const unsigned int*)mask;
  const int byteLayout = __any(mwp[tid] > 1u);

  for (int i = tid; i < 6144; i += 512) lds[i] = 0;
  if (flat < 128 && tid < 193) {        // pre-zero dispatch-2 counters
    int zi = flat * 193 + tid;
    if (zi < ZERO_N) ws[ZERO_I + zi] = 0;
  }

  int c01 = 0, c23 = 0, c45 = 0;

  // voxel: 6 mask bits at shift SH of the 6 mask dwords; bin once per voxel
#define VOX(SH, M, PP, GG)                                                   \
  {                                                                          \
    int a01 = (((M)[0] >> (SH)) & 1) | ((((M)[1] >> (SH)) & 1) << 16);       \
    int a23 = (((M)[2] >> (SH)) & 1) | ((((M)[3] >> (SH)) & 1) << 16);       \
    int a45 = (((M)[4] >> (SH)) & 1) | ((((M)[5] >> (SH)) & 1) << 16);       \
    int bp = min((int)((PP) * 1024.0f), NB1);                                \
    int bg = min((int)((GG) * 1024.0f), NB1);                                \
    atomicAdd(&lds[bp],        a01); atomicAdd(&lds[1024 + bp], a23);        \
    atomicAdd(&lds[2048 + bp], a45);                                         \
    atomicAdd(&lds[3072 + bg], a01); atomicAdd(&lds[4096 + bg], a23);        \
    atomicAdd(&lds[5120 + bg], a45);                                         \
    c01 += a01; c23 += a23; c45 += a45;                                      \
  }

  if (byteLayout) {
    const char* pbase = (const char*)(pred + (size_t)b * VVOX + v0);
    const char* gbase = (const char*)(tgt  + (size_t)b * VVOX + v0);
    const char* mbase = (const char*)mask;

    // 14 x 1KB DMA slots per tile: 0-3 pred, 4-7 tgt, 8-13 masks.
    // Wave w issues slots {w, w+8} (w<6) or {w} (w=6,7): P(w) = 2 or 1.
    auto issue = [&](int t) {
      const int base = BUF0_I + (t % NBUF) * BUFSZ;
      for (int j = wid; j < NSLOT; j += 8) {
        const char* src;
        int dsti;                        // int index into lds[]
        if (j < 4) {
          src = pbase + t * 4096 + j * 1024;       dsti = base + j * 256;
        } else if (j < 8) {
          src = gbase + t * 4096 + (j - 4) * 1024; dsti = base + 1024 + (j - 4) * 256;
        } else {
          int r = j - 8;
          src = mbase + (size_t)(r * BPAT + b) * VVOX + v0 + t * TILE;
          dsti = base + 2048 + r * 256;
        }
        __builtin_amdgcn_global_load_lds(
            (glb_t*)(src + lane * 16),
            (lds_t*)((char*)lds + (size_t)dsti * 4), 16, 0, 0);
      }
    };

    // Drain everything once: ws-zero stores + byteLayout load (vmcnt) and
    // hist-zero LDS writes (lgkmcnt) -- counted waits below assume only
    // tile DMAs are outstanding.
    VWAIT("vmcnt(0) lgkmcnt(0)");
    issue(0);
    issue(1);

#pragma unroll
    for (int t = 0; t < NTILE; t++) {
      // wait until tile t's own loads retired (in-order vmcnt), leaving
      // tile t+1's P(w) loads in flight; drain fully only on last tile
      if (t < NTILE - 1) {
        if (wid < 6) VWAIT("vmcnt(2)");
        else         VWAIT("vmcnt(1)");
      } else {
        VWAIT("vmcnt(0)");
      }
      __builtin_amdgcn_s_barrier();   // all waves' tile-t data visible;
      CFENCE();                       //  and all compute(t-1) reads done
      if (t + 2 < NTILE) issue(t + 2);  // overwrite buf[(t-1)%3] -- safe now

      // compute tile t: this thread owns tile voxels {2*tid, 2*tid+1}
      const int base = BUF0_I + (t % NBUF) * BUFSZ;
      float2 pv = *(const float2*)&lds[base + tid * 2];
      float2 gv = *(const float2*)&lds[base + 1024 + tid * 2];
      unsigned m[RROI];
#pragma unroll
      for (int r = 0; r < RROI; r++)
        m[r] = *(const unsigned*)&lds[base + 2048 + r * 256 + (tid >> 1)];
      const int sh = (tid & 1) << 4;   // byte 2*(tid&1) of each mask word
      VOX(sh,     m, pv.x, gv.x)
      VOX(sh + 8, m, pv.y, gv.y)
    }
  } else {  // int32 masks — correctness-only path, direct loads
    __syncthreads();
    const int* mi = (const int*)mask;
    const float4* p4 = (const float4*)(pred + (size_t)b * VVOX + v0);
    const float4* g4 = (const float4*)(tgt  + (size_t)b * VVOX + v0);
    for (int pk = tid; pk < CHUNK / 4; pk += 512) {
      float4 pv = p4[pk], gv = g4[pk];
      unsigned m0[RROI], m1[RROI], m2[RROI], m3[RROI];
#pragma unroll
      for (int r = 0; r < RROI; r++) {
        int4 mm = ((const int4*)(mi + (size_t)(r * BPAT + b) * VVOX + v0))[pk];
        m0[r] = mm.x; m1[r] = mm.y; m2[r] = mm.z; m3[r] = mm.w;
      }
      VOX(0, m0, pv.x, gv.x)
      VOX(0, m1, pv.y, gv.y)
      VOX(0, m2, pv.z, gv.z)
      VOX(0, m3, pv.w, gv.w)
    }
    __syncthreads();
  }
#undef VOX

  // count merge: buffer 0 is free now (tile 7 used buffer 1); all waves'
  // compute(6) on buffer 0 finished before the t=7 barrier.
  if (tid < 3) lds[BUF_I + tid] = 0;
  __syncthreads();
  for (int off = 32; off > 0; off >>= 1) {
    c01 += __shfl_down(c01, off, 64);
    c23 += __shfl_down(c23, off, 64);
    c45 += __shfl_down(c45, off, 64);
  }
  if (lane == 0) {
    atomicAdd(&lds[BUF_I], c01); atomicAdd(&lds[BUF_I + 1], c23);
    atomicAdd(&lds[BUF_I + 2], c45);
  }
  __syncthreads();

  // write signed int16 diffs (pred-tgt), 2 bins per int
  for (int idx = tid; idx < RROI * HW; idx += 512) {   // 6 iters
    int r = idx >> 9, wd = idx & (HW - 1);
    int k = r >> 1, f = (r & 1) << 4;
    int b0 = 2 * wd, b1 = b0 + 1;
    int d0 = ((lds[k * 1024 + b0] >> f) & 0xffff) -
             ((lds[(3 + k) * 1024 + b0] >> f) & 0xffff);
    int d1 = ((lds[k * 1024 + b1] >> f) & 0xffff) -
             ((lds[(3 + k) * 1024 + b1] >> f) & 0xffff);
    ws[PART_I + (size_t)(flat * RROI + r) * HW + wd] = (d0 & 0xffff) | (d1 << 16);
  }
  if (tid < RROI) {
    int p = lds[BUF_I + (tid >> 1)];
    int c = (tid & 1) ? ((p >> 16) & 0xffff) : (p & 0xffff);
    ws[CNT6_I + flat * RROI + tid] = c;
  }
}

// ---- phase 2: reduce quarters -> global merge -> winner scan -> finalize -
__global__ __launch_bounds__(256) void seg_scan(int* __restrict__ ws,
                                                float* __restrict__ out) {
  const int bq  = blockIdx.x;          // 0..95
  const int seg = bq >> 2, q = bq & 3;
  const int r   = seg >> 2, b = seg & 3;
  const int t   = threadIdx.x;         // 256 threads; each owns bins 4t..4t+3

  int s[4] = {0, 0, 0, 0};
#pragma unroll 4
  for (int nb = q * 32; nb < q * 32 + 32; nb++) {
    const int2 wv = ((const int2*)(ws + PART_I +
                     (size_t)((b * BLKP + nb) * RROI + r) * HW))[t];
    s[0] += (int)(short)(wv.x & 0xffff); s[1] += wv.x >> 16;
    s[2] += (int)(short)(wv.y & 0xffff); s[3] += wv.y >> 16;
  }
  int* fh = ws + FH_I + seg * NBINS + 4 * t;
#pragma unroll
  for (int k = 0; k < 4; k++)
    if (s[k]) atomicAdd(&fh[k], s[k]);
  __threadfence();
  __shared__ int winflag;
  if (t == 0) winflag = (atomicAdd(ws + DONE_I + seg, 1) == 3);
  __syncthreads();
  if (!winflag) return;

  int bins[4];
#pragma unroll
  for (int k = 0; k < 4; k++)
    bins[k] = __hip_atomic_load(&fh[k], __ATOMIC_RELAXED,
                                __HIP_MEMORY_SCOPE_AGENT);
  int dv = (t < BLKP) ? ws[CNT6_I + (b * BLKP + t) * RROI + r] : 0;

  int tot = 0;
#pragma unroll
  for (int k = 0; k < 4; k++) { tot += bins[k]; bins[k] = tot; }
  const int lane = t & 63, wid = t >> 6;       // 4 waves
  int v = tot;
  for (int off = 1; off < 64; off <<= 1) {
    int u = __shfl_up(v, off, 64);
    if (lane >= off) v += u;
  }
  __shared__ int wsum[4]; __shared__ unsigned long long lsum[4];
  __shared__ int dsum[4];
  if (lane == 63) wsum[wid] = v;
  for (int off = 32; off > 0; off >>= 1) dv += __shfl_down(dv, off, 64);
  if (lane == 0) dsum[wid] = dv;
  __syncthreads();
  int woff = 0;
  for (int w = 0; w < wid; w++) woff += wsum[w];
  const int excl = woff + v - tot;
  unsigned long long acc = 0;
#pragma unroll
  for (int k = 0; k < 4; k++) {
    int c = excl + bins[k];
    acc += (unsigned long long)(c < 0 ? -c : c);
  }
  for (int off = 32; off > 0; off >>= 1) acc += __shfl_down(acc, off, 64);
  if (lane == 0) lsum[wid] = acc;
  __syncthreads();

  if (t == 0) {
    unsigned long long a = 0; int d = 0;
    for (int w = 0; w < 4; w++) { a += lsum[w]; d += dsum[w]; }
    ((float*)ws)[S_I + seg] = (float)((double)a * (52.0 / (double)NBINS));
    ws[DEN_I + seg] = d;
    __threadfence();
    if (atomicAdd(ws + SEGD_I, 1) == NSEG - 1) {   // last segment finalizes
      float total = 0.f; int nv = 0;
      for (int bb = 0; bb < BPAT; bb++) {
        float num = 0.f; long long dd = 0;
        for (int rr = 0; rr < RROI; rr++) {
          num += __hip_atomic_load(&((float*)ws)[S_I + rr * BPAT + bb],
                                   __ATOMIC_RELAXED, __HIP_MEMORY_SCOPE_AGENT);
          dd  += __hip_atomic_load(&ws[DEN_I + rr * BPAT + bb],
                                   __ATOMIC_RELAXED, __HIP_MEMORY_SCOPE_AGENT);
        }
        if (dd > 0) { total += num / fmaxf((float)dd, 1.f); nv++; }
      }
      out[0] = total / (float)(nv > 0 ? nv : 1);
    }
  }
}

extern "C" void kernel_launch(void* const* d_in, const int* in_sizes, int n_in,
                              void* d_out, int out_size, void* d_ws,
                              size_t ws_size, hipStream_t stream) {
  const float* pred = (const float*)d_in[0];
  const float* tgt  = (const float*)d_in[1];
  const void* mask  = d_in[2];
  int* ws = (int*)d_ws;   // needs ~6.5 MB; d_ws is 384 MiB

  hist_kernel<<<GRID1, 512, 0, stream>>>(pred, tgt, mask, ws);
  seg_scan<<<NSEG * 4, 256, 0, stream>>>(ws, (float*)d_out);
}